// Round 5
// baseline (300.134 us; speedup 1.0000x reference)
//
#include <hip/hip_runtime.h>
#include <hip/hip_bf16.h>

// Problem constants
#define BB 2
#define LL 5000
#define CIN 256
#define CLOI 128
#define HH 256
#define WW 256
#define HWP (HH*WW)
#define NPTS0 32
#define NPTS1 8
#define PLANES 64
#define EPSV 1e-5f

// workspace layout (bytes)
#define X_BYTES   ((size_t)BB * HWP * CLOI * 2)            // 33,554,432: fc1 map bf16 channel-last
#define XS_BYTES  ((size_t)BB * LL * 1024 * 2)             // 20,480,000: xs bf16 swizzled [line][kg16][t8][8]
#define W1S_OFF   (X_BYTES + XS_BYTES)                     // 8192 bf16 = 16384 B   [16kg][64m][8]
#define W2S_OFF   (W1S_OFF + 16384)                        // 12288 bf16 = 24576 B  [3dt][8kg][64m][8]
#define W3S_OFF   (W2S_OFF + 24576)                        // 8192 bf16 = 16384 B   [8kg][128m][8]
#define B1P_OFF   (W3S_OFF + 16384)                        // 64 f32
#define B2P_OFF   (B1P_OFF + 256)                          // 64 f32
#define S1_OFF    (B2P_OFF + 256)                          // 128 f32
#define T1_OFF    (S1_OFF + 512)                           // 128 f32
#define W0S_OFF   (T1_OFF + 512)                           // fc1_w bf16 swizzled [32grp][128m][8] = 65536 B

typedef unsigned int uint;
typedef unsigned short ushort;
typedef __attribute__((ext_vector_type(8))) short short8;
typedef __attribute__((ext_vector_type(4))) float f32x4;

__device__ __forceinline__ float bfLow(uint u)  { return __uint_as_float(u << 16); }
__device__ __forceinline__ float bfHigh(uint u) { return __uint_as_float(u & 0xffff0000u); }
__device__ __forceinline__ float bf2f(ushort u) { return __uint_as_float(((uint)u) << 16); }
__device__ __forceinline__ ushort f2bf(float f) {
    uint x = __float_as_uint(f);
    uint r = (x + 0x7fffu + ((x >> 16) & 1u)) >> 16;   // RNE
    return (ushort)r;
}
// HW packed convert: v_cvt_pk_bf16_f32 on gfx950 (RNE), a -> low16, b -> high16
__device__ __forceinline__ uint pk2(float a, float b) {
    float2 f; f.x = a; f.y = b;
    __hip_bfloat162 h = __float22bfloat162_rn(f);
    uint r;
    __builtin_memcpy(&r, &h, 4);
    return r;
}

// ---------------------------------------------------------------------------
// Kernel A: fc1 1x1 conv as bf16 MFMA GEMM.
// Block = 64 pixels x 128 outputs x K=256, single LDS stage + 1 barrier.
// ---------------------------------------------------------------------------
__global__ __launch_bounds__(256) void fc1_kernel(
    const float* __restrict__ feature, const ushort* __restrict__ w0s,
    const float* __restrict__ fc1_b, ushort* __restrict__ xout)
{
    __shared__ ushort sF[32 * 64 * 8];   // [grp(k/8)][px][j] bf16, 32 KB

    int tid = threadIdx.x;
    int tile = blockIdx.x;               // 0..2047
    int b = tile >> 10;
    int p0 = (tile & 1023) << 6;
    int wv = tid >> 6, lane = tid & 63;
    int q = lane >> 4, ln = lane & 15;

    // preload A-frags: k = kg*32 + q*8 + j, m = wv*32 + mt*16 + ln
    short8 afr[8][2];
#pragma unroll
    for (int kg = 0; kg < 8; kg++)
#pragma unroll
        for (int mt = 0; mt < 2; mt++)
            afr[kg][mt] = *(const short8*)(w0s + ((size_t)((kg * 4 + q) * 128 + wv * 32 + mt * 16 + ln)) * 8);

    // stage feature tile -> bf16 LDS (B-frag layout), HW packed converts
    const float* fb = feature + (size_t)b * CIN * HWP + p0;
    int g_ = tid >> 4;                   // 0..15
    int qd = tid & 15;                   // pixel quad
#pragma unroll
    for (int s = 0; s < 2; s++) {
        int g = s * 16 + g_;             // channel group 0..31 (8 ch each)
        const float* src = fb + (size_t)(g * 8) * HWP + qd * 4;
        float4 rv[8];
#pragma unroll
        for (int j = 0; j < 8; j++) rv[j] = *(const float4*)(src + (size_t)j * HWP);
#pragma unroll
        for (int i = 0; i < 4; i++) {
            uint4 u;
            u.x = pk2(((const float*)&rv[0])[i], ((const float*)&rv[1])[i]);
            u.y = pk2(((const float*)&rv[2])[i], ((const float*)&rv[3])[i]);
            u.z = pk2(((const float*)&rv[4])[i], ((const float*)&rv[5])[i]);
            u.w = pk2(((const float*)&rv[6])[i], ((const float*)&rv[7])[i]);
            *(uint4*)(&sF[(g * 64 + qd * 4 + i) * 8]) = u;
        }
    }
    __syncthreads();

    const f32x4 fzero = { 0.f, 0.f, 0.f, 0.f };
    f32x4 acc[2][4];
#pragma unroll
    for (int mt = 0; mt < 2; mt++)
#pragma unroll
        for (int nt = 0; nt < 4; nt++) acc[mt][nt] = fzero;

#pragma unroll
    for (int kg = 0; kg < 8; kg++) {
#pragma unroll
        for (int nt = 0; nt < 4; nt++) {
            short8 bfr = *(short8*)(&sF[((kg * 4 + q) * 64 + nt * 16 + ln) * 8]);
            acc[0][nt] = __builtin_amdgcn_mfma_f32_16x16x32_bf16(afr[kg][0], bfr, acc[0][nt], 0, 0, 0);
            acc[1][nt] = __builtin_amdgcn_mfma_f32_16x16x32_bf16(afr[kg][1], bfr, acc[1][nt], 0, 0, 0);
        }
    }

    float bias[8];
    *(float4*)bias       = *(const float4*)(fc1_b + wv * 32 + q * 4);
    *(float4*)(bias + 4) = *(const float4*)(fc1_b + wv * 32 + 16 + q * 4);
    ushort* xrow = xout + (size_t)b * HWP * CLOI;
#pragma unroll
    for (int mt = 0; mt < 2; mt++)
#pragma unroll
        for (int nt = 0; nt < 4; nt++) {
            uint2 u;
            u.x = pk2(acc[mt][nt][0] + bias[mt * 4 + 0], acc[mt][nt][1] + bias[mt * 4 + 1]);
            u.y = pk2(acc[mt][nt][2] + bias[mt * 4 + 2], acc[mt][nt][3] + bias[mt * 4 + 3]);
            *(uint2*)(xrow + (size_t)(p0 + nt * 16 + ln) * CLOI + wv * 32 + mt * 16 + q * 4) = u;
        }
}

// ---------------------------------------------------------------------------
// Prep kernel: fold BNs, swizzle weights to bf16 A-frag layouts.
// ---------------------------------------------------------------------------
__global__ __launch_bounds__(256) void prep_kernel(
    const float* __restrict__ conv1_w, const float* __restrict__ conv1_b,
    const float* __restrict__ bn2_g, const float* __restrict__ bn2_b,
    const float* __restrict__ bn2_m, const float* __restrict__ bn2_v,
    const float* __restrict__ conv2_w, const float* __restrict__ conv2_b,
    const float* __restrict__ bn3_g, const float* __restrict__ bn3_b,
    const float* __restrict__ bn3_m, const float* __restrict__ bn3_v,
    const float* __restrict__ conv3_w,
    const float* __restrict__ bn1_g, const float* __restrict__ bn1_b,
    const float* __restrict__ bn1_m, const float* __restrict__ bn1_v,
    const float* __restrict__ fc1_w,
    ushort* __restrict__ w1s, ushort* __restrict__ w2s, ushort* __restrict__ w3s,
    float* __restrict__ b1p, float* __restrict__ b2p,
    float* __restrict__ s1o, float* __restrict__ t1o,
    ushort* __restrict__ w0s)
{
    int idx = blockIdx.x * 256 + threadIdx.x;
    if (idx < 8192) {   // W1s [16kg][64m][8], fold s2
        int kg = idx >> 9, rem = idx & 511, m = rem >> 3, j = rem & 7;
        int c = kg * 8 + j;
        float s2 = bn2_g[m] * rsqrtf(bn2_v[m] + EPSV);
        w1s[idx] = f2bf(conv1_w[m * 128 + c] * s2);
    }
    if (idx < 12288) {  // W2s [3dt][8kg][64m][8], fold s3
        int dt = idx >> 12, rem = idx & 4095;
        int kg = rem >> 9, m = (rem >> 3) & 63, j = rem & 7;
        int i = kg * 8 + j;
        float s3 = bn3_g[m] * rsqrtf(bn3_v[m] + EPSV);
        w2s[idx] = f2bf(conv2_w[m * 192 + i * 3 + dt] * s3);
    }
    if (idx < 8192) {   // W3s [8kg][128m][8]
        int kg = idx >> 10, rem = idx & 1023, m = rem >> 3, j = rem & 7;
        w3s[idx] = f2bf(conv3_w[m * 64 + kg * 8 + j]);
    }
    if (idx < 32768) {  // W0s [32grp][128m][8] from fc1_w [128m][256c]
        int grp = idx >> 10, rem = idx & 1023, m = rem >> 3, j = rem & 7;
        w0s[idx] = f2bf(fc1_w[m * CIN + grp * 8 + j]);
    }
    if (idx < 64) {
        float s2 = bn2_g[idx] * rsqrtf(bn2_v[idx] + EPSV);
        b1p[idx] = conv1_b[idx] * s2 + bn2_b[idx] - bn2_m[idx] * s2;
        float s3 = bn3_g[idx] * rsqrtf(bn3_v[idx] + EPSV);
        b2p[idx] = conv2_b[idx] * s3 + bn3_b[idx] - bn3_m[idx] * s3;
    }
    if (idx < 128) {
        float s1 = bn1_g[idx] * rsqrtf(bn1_v[idx] + EPSV);
        s1o[idx] = s1;
        t1o[idx] = bn1_b[idx] - bn1_m[idx] * s1;
    }
}

// ---------------------------------------------------------------------------
// Kernel B1: bilinear sample + maxpool.
// p in [-0.5, 254.5] => x1=x0+1, y1=y0+1 always -> 4 neighbors form two
// contiguous 512B blocks. Wave loads each block as 64x uint2 (lanes<32 = y0
// row, lanes>=32 = y1 row), x-interps per half, combines halves via
// shfl_xor(32). Half h owns pool group 2wv+h.
// ---------------------------------------------------------------------------
__global__ __launch_bounds__(256) void sample_kernel(
    const ushort* __restrict__ x, const float* __restrict__ lines,
    ushort* __restrict__ xsb)
{
    __shared__ int    sBase[NPTS0];
    __shared__ float4 sW4[NPTS0];

    int n = blockIdx.x;
    int b = n / LL;
    int tid = threadIdx.x;

    if (tid < NPTS0) {
        int j = tid;
        float lam = (float)j * (1.0f / 31.0f);
        const float* lp = lines + (size_t)n * 4;
        float e0x = lp[0], e0y = lp[1], e1x = lp[2], e1y = lp[3];
        float px = e0x * lam + e1x * (1.f - lam) - 0.5f;
        float py = e0y * lam + e1y * (1.f - lam) - 0.5f;
        float px0 = fminf(fmaxf(floorf(px), 0.f), 255.f);
        float py0 = fminf(fmaxf(floorf(py), 0.f), 255.f);
        float px1 = px0 + 1.f;
        float py1 = py0 + 1.f;
        int ix0 = (int)px0, iy0 = (int)py0;
        sBase[j] = (ix0 * WW + iy0) * 256;       // byte offset of (x0,y0) pixel
        float4 w;
        w.x = (px1 - px) * (py1 - py);           // w00 (x0,y0)
        w.y = (px - px0) * (py1 - py);           // w10 (x1,y0)
        w.z = (px1 - px) * (py - py0);           // w01 (x0,y1)
        w.w = (px - px0) * (py - py0);           // w11 (x1,y1)
        sW4[j] = w;
    }
    __syncthreads();

    int wv = tid >> 6, lane = tid & 63;
    bool hiHalf = lane >= 32;
    int loff = lane * 8;                          // lanes<32: y0 pixel; >=32: y1 pixel
    const char* xbc = (const char*)(x + (size_t)b * HWP * CLOI);

    float m0 = -INFINITY, m1 = -INFINITY, m2 = -INFINITY, m3 = -INFINITY;

#pragma unroll
    for (int jj = 0; jj < 8; jj++) {
        int j = wv * 8 + jj;
        int b0 = sBase[j];
        float4 w4 = sW4[j];
        int rb0 = __builtin_amdgcn_readfirstlane(b0);
        const char* pA = xbc + rb0;               // (x0, y0..y1) 512B block
        const char* pB = pA + 65536;              // (x0+1, y0..y1) block
        uint2 l1 = *(const uint2*)(pA + loff);
        uint2 l2 = *(const uint2*)(pB + loff);
        float wA = hiHalf ? w4.z : w4.x;
        float wB = hiHalf ? w4.w : w4.y;
        float t0 = bfLow(l1.x) * wA + bfLow(l2.x) * wB;
        float t1 = bfHigh(l1.x) * wA + bfHigh(l2.x) * wB;
        float t2 = bfLow(l1.y) * wA + bfLow(l2.y) * wB;
        float t3 = bfHigh(l1.y) * wA + bfHigh(l2.y) * wB;
        t0 += __shfl_xor(t0, 32);
        t1 += __shfl_xor(t1, 32);
        t2 += __shfl_xor(t2, 32);
        t3 += __shfl_xor(t3, 32);
        if ((jj >= 4) == hiHalf) {
            m0 = fmaxf(m0, t0); m1 = fmaxf(m1, t1);
            m2 = fmaxf(m2, t2); m3 = fmaxf(m3, t3);
        }
    }

    // half h owns pool group t = 2*wv + h; lane covers channels c0..c0+3
    int t = 2 * wv + (hiHalf ? 1 : 0);
    int c0 = (lane & 31) * 4;
    int kg = c0 >> 3;
    uint2 u; u.x = pk2(m0, m1); u.y = pk2(m2, m3);
    *(uint2*)(xsb + (size_t)n * 1024 + kg * 64 + t * 8 + (c0 & 7)) = u;
}

// ---------------------------------------------------------------------------
// Kernel B2: MFMA head. 8 lines/block, 4 waves. LDS trimmed to ~43KB
// (3 blocks/CU); fc2 weights read direct from global (L1/L2-resident).
// ---------------------------------------------------------------------------
__global__ __launch_bounds__(256) void head_kernel(
    const ushort* __restrict__ xsb,
    const ushort* __restrict__ w1s, const ushort* __restrict__ w2s,
    const ushort* __restrict__ w3s,
    const float* __restrict__ b1p, const float* __restrict__ b2p,
    const float* __restrict__ s1g, const float* __restrict__ t1g,
    const float* __restrict__ conv3_b,
    const float* __restrict__ fc2_w, const float* __restrict__ fc2_b,
    float* __restrict__ out)
{
    __shared__ ushort sXS[8192];   // [16kg][64col][8] raw xs bf16
    __shared__ ushort sH1[8192];   // h1; later reused as conv2 out
    __shared__ ushort sB2[4096];   // [8kg][64col][8] conv1 out
    __shared__ float  sS1[128], sT1[128];
    __shared__ float  sB1[64], sB2b[64], sB3b[128];

    int tid = threadIdx.x;
    int wv = tid >> 6, lane = tid & 63;
    int q = lane >> 4, ln = lane & 15;
    int L0 = blockIdx.x * 8;
    int colg = wv * 16 + ln;

    if (tid < 128) { sS1[tid] = s1g[tid]; sT1[tid] = t1g[tid]; sB3b[tid] = conv3_b[tid]; }
    if (tid < 64)  { sB1[tid] = b1p[tid]; sB2b[tid] = b2p[tid]; }
    __syncthreads();

    // ---- stage xs tile + h1 = relu(bn1(xs)) ----
#pragma unroll
    for (int it = 0; it < 4; it++) {
        int ch = it * 256 + tid;          // 0..1023
        int l = ch >> 7, wc = ch & 127;
        int kg = wc >> 3, tt = wc & 7;
        int col = l * 8 + tt;
        uint4 raw = *(const uint4*)(xsb + (size_t)(L0 + l) * 1024 + wc * 8);
        int off = (kg * 64 + col) * 8;
        *(uint4*)(&sXS[off]) = raw;
        uint rw[4] = { raw.x, raw.y, raw.z, raw.w };
        uint hw[4];
#pragma unroll
        for (int p = 0; p < 4; p++) {
            int c = kg * 8 + p * 2;
            float h0  = fmaxf(bfLow(rw[p])  * sS1[c]     + sT1[c],     0.f);
            float h1v = fmaxf(bfHigh(rw[p]) * sS1[c + 1] + sT1[c + 1], 0.f);
            hw[p] = pk2(h0, h1v);
        }
        uint4 hv; hv.x = hw[0]; hv.y = hw[1]; hv.z = hw[2]; hv.w = hw[3];
        *(uint4*)(&sH1[off]) = hv;
    }
    __syncthreads();

    const short8 bzero = { 0, 0, 0, 0, 0, 0, 0, 0 };
    const f32x4 fzero = { 0.f, 0.f, 0.f, 0.f };

    // ---- conv1: M=64, K=128 ----
    f32x4 acc1[4];
#pragma unroll
    for (int mt = 0; mt < 4; mt++) acc1[mt] = fzero;
#pragma unroll
    for (int ks = 0; ks < 4; ks++) {
        short8 b = *(short8*)(&sH1[((ks * 4 + q) * 64 + colg) * 8]);
#pragma unroll
        for (int mt = 0; mt < 4; mt++) {
            short8 a = *(const short8*)(w1s + ((ks * 4 + q) * 64 + mt * 16 + ln) * 8);
            acc1[mt] = __builtin_amdgcn_mfma_f32_16x16x32_bf16(a, b, acc1[mt], 0, 0, 0);
        }
    }
#pragma unroll
    for (int mt = 0; mt < 4; mt++) {
        int m0 = mt * 16 + q * 4;
        float v0 = fmaxf(acc1[mt][0] + sB1[m0 + 0], 0.f);
        float v1 = fmaxf(acc1[mt][1] + sB1[m0 + 1], 0.f);
        float v2 = fmaxf(acc1[mt][2] + sB1[m0 + 2], 0.f);
        float v3 = fmaxf(acc1[mt][3] + sB1[m0 + 3], 0.f);
        uint2 u; u.x = pk2(v0, v1); u.y = pk2(v2, v3);
        *(uint2*)(&sB2[((m0 >> 3) * 64 + colg) * 8 + (m0 & 7)]) = u;
    }
    __syncthreads();

    // ---- conv2: M=64, K=64 x 3 taps ----
    f32x4 acc2[4];
#pragma unroll
    for (int mt = 0; mt < 4; mt++) acc2[mt] = fzero;
    int tpos = colg & 7;
#pragma unroll
    for (int dt = 0; dt < 3; dt++) {
        int tsh = tpos + dt - 1;
        bool valid = ((unsigned)tsh < 8u);
        int colr = colg + dt - 1;
        colr = colr < 0 ? 0 : (colr > 63 ? 63 : colr);
#pragma unroll
        for (int ks = 0; ks < 2; ks++) {
            short8 b = *(short8*)(&sB2[((ks * 4 + q) * 64 + colr) * 8]);
            b = valid ? b : bzero;
#pragma unroll
            for (int mt = 0; mt < 4; mt++) {
                short8 a = *(const short8*)(w2s + dt * 4096 + ((ks * 4 + q) * 64 + mt * 16 + ln) * 8);
                acc2[mt] = __builtin_amdgcn_mfma_f32_16x16x32_bf16(a, b, acc2[mt], 0, 0, 0);
            }
        }
    }
#pragma unroll
    for (int mt = 0; mt < 4; mt++) {
        int m0 = mt * 16 + q * 4;
        float v0 = fmaxf(acc2[mt][0] + sB2b[m0 + 0], 0.f);
        float v1 = fmaxf(acc2[mt][1] + sB2b[m0 + 1], 0.f);
        float v2 = fmaxf(acc2[mt][2] + sB2b[m0 + 2], 0.f);
        float v3 = fmaxf(acc2[mt][3] + sB2b[m0 + 3], 0.f);
        uint2 u; u.x = pk2(v0, v1); u.y = pk2(v2, v3);
        *(uint2*)(&sH1[((m0 >> 3) * 64 + colg) * 8 + (m0 & 7)]) = u;
    }
    __syncthreads();

    // ---- conv3: M=128, K=64 ----
    f32x4 acc3[8];
#pragma unroll
    for (int mt = 0; mt < 8; mt++) acc3[mt] = fzero;
#pragma unroll
    for (int ks = 0; ks < 2; ks++) {
        short8 b = *(short8*)(&sH1[((ks * 4 + q) * 64 + colg) * 8]);
#pragma unroll
        for (int mt = 0; mt < 8; mt++) {
            short8 a = *(const short8*)(w3s + ((ks * 4 + q) * 128 + mt * 16 + ln) * 8);
            acc3[mt] = __builtin_amdgcn_mfma_f32_16x16x32_bf16(a, b, acc3[mt], 0, 0, 0);
        }
    }

    // ---- residual + relu + fc2 (fc2_w direct from global, b64 xs reads) ----
    float p0 = 0.f, p1 = 0.f, p2 = 0.f;
#pragma unroll
    for (int mt = 0; mt < 8; mt++) {
        int m0 = mt * 16 + q * 4;
        int kg = m0 >> 3;
        uint2 xr = *(uint2*)(&sXS[kg * 512 + colg * 8 + (m0 & 7)]);
        float xsv[4] = { bfLow(xr.x), bfHigh(xr.x), bfLow(xr.y), bfHigh(xr.y) };
#pragma unroll
        for (int r = 0; r < 4; r++) {
            int m = m0 + r;
            float v = fmaxf(xsv[r] + acc3[mt][r] + sB3b[m], 0.f);
            int fi = m * 8 + tpos;
            p0 += v * fc2_w[fi];
            p1 += v * fc2_w[1024 + fi];
            p2 += v * fc2_w[2048 + fi];
        }
    }
    p0 += __shfl_xor(p0, 32); p1 += __shfl_xor(p1, 32); p2 += __shfl_xor(p2, 32);
    p0 += __shfl_xor(p0, 16); p1 += __shfl_xor(p1, 16); p2 += __shfl_xor(p2, 16);
    p0 += __shfl_xor(p0, 4);  p1 += __shfl_xor(p1, 4);  p2 += __shfl_xor(p2, 4);
    p0 += __shfl_xor(p0, 2);  p1 += __shfl_xor(p1, 2);  p2 += __shfl_xor(p2, 2);
    p0 += __shfl_xor(p0, 1);  p1 += __shfl_xor(p1, 1);  p2 += __shfl_xor(p2, 1);

    if (lane == 0 || lane == 8) {
        int line = L0 + wv * 2 + (lane >> 3);
        out[(size_t)line * 3 + 0] = p0 + fc2_b[0];
        out[(size_t)line * 3 + 1] = p1 + fc2_b[1];
        out[(size_t)line * 3 + 2] = p2 + fc2_b[2];
    }
}

extern "C" void kernel_launch(void* const* d_in, const int* in_sizes, int n_in,
                              void* d_out, int out_size, void* d_ws, size_t ws_size,
                              hipStream_t stream) {
    const float* feature = (const float*)d_in[0];
    const float* lines   = (const float*)d_in[1];
    const float* fc1_w   = (const float*)d_in[2];
    const float* fc1_b   = (const float*)d_in[3];
    const float* bn1_g   = (const float*)d_in[4];
    const float* bn1_b   = (const float*)d_in[5];
    const float* bn1_m   = (const float*)d_in[6];
    const float* bn1_v   = (const float*)d_in[7];
    const float* conv1_w = (const float*)d_in[8];
    const float* conv1_b = (const float*)d_in[9];
    const float* bn2_g   = (const float*)d_in[10];
    const float* bn2_b   = (const float*)d_in[11];
    const float* bn2_m   = (const float*)d_in[12];
    const float* bn2_v   = (const float*)d_in[13];
    const float* conv2_w = (const float*)d_in[14];
    const float* conv2_b = (const float*)d_in[15];
    const float* bn3_g   = (const float*)d_in[16];
    const float* bn3_b   = (const float*)d_in[17];
    const float* bn3_m   = (const float*)d_in[18];
    const float* bn3_v   = (const float*)d_in[19];
    const float* conv3_w = (const float*)d_in[20];
    const float* conv3_b = (const float*)d_in[21];
    const float* fc2_w   = (const float*)d_in[22];
    const float* fc2_b   = (const float*)d_in[23];
    float* out = (float*)d_out;

    char* ws = (char*)d_ws;
    ushort* x_bf = (ushort*)ws;
    ushort* xs_b = (ushort*)(ws + X_BYTES);
    ushort* w1s  = (ushort*)(ws + W1S_OFF);
    ushort* w2s  = (ushort*)(ws + W2S_OFF);
    ushort* w3s  = (ushort*)(ws + W3S_OFF);
    float*  b1p  = (float*)(ws + B1P_OFF);
    float*  b2p  = (float*)(ws + B2P_OFF);
    float*  s1g  = (float*)(ws + S1_OFF);
    float*  t1g  = (float*)(ws + T1_OFF);
    ushort* w0s  = (ushort*)(ws + W0S_OFF);

    prep_kernel<<<128, 256, 0, stream>>>(
        conv1_w, conv1_b, bn2_g, bn2_b, bn2_m, bn2_v,
        conv2_w, conv2_b, bn3_g, bn3_b, bn3_m, bn3_v,
        conv3_w, bn1_g, bn1_b, bn1_m, bn1_v, fc1_w,
        w1s, w2s, w3s, b1p, b2p, s1g, t1g, w0s);
    fc1_kernel<<<2048, 256, 0, stream>>>(feature, w0s, fc1_b, x_bf);
    sample_kernel<<<BB * LL, 256, 0, stream>>>(x_bf, lines, xs_b);
    head_kernel<<<BB * LL / 8, 256, 0, stream>>>(
        xs_b, w1s, w2s, w3s, b1p, b2p, s1g, t1g, conv3_b, fc2_w, fc2_b, out);
}